// Round 10
// baseline (212.938 us; speedup 1.0000x reference)
//
#include <hip/hip_runtime.h>
#include <hip/hip_bf16.h>

// ConvIntrinsic: gather+barycentric -> patch-operator -> 8 rotated folds.
// Circular-correlation FFT formulation (verified R8/R9): 8-pt real DFT over
// the angular index on both sides; ĉ[k]=X*[k]Y[k] per bin k={0&4,1,2,3};
// in-register inverse DFT + bias + relu + k-pair fold in the GEMM epilogue.
//
// R10: (a) prep de-eviction experiment — ALL prep outputs stored
// non-temporal (keep per-XCD L2 holding the mesh), mesh pre-converted to
// bf16 (1.5 MB, L2-resident; half gather bytes), prep TLP x2 (1500 blocks,
// (point, rho-half) slots). Theory: prep's ~85us is gathers missing L2
// because the 61 MB Ahat write stream evicts the 3 MB mesh.
// (b) GEMM BK=128: 16 MFMAs per barrier pair (was 8), half the barrier
// drains; LDS 40 KB -> still 4 blocks/CU. 4-bit XOR chunk swizzle keeps
// ds_read_b128 at 2 lanes/bank (free).

#define N_PTS 6000
#define RR 5
#define AA 8
#define FF 128
#define OO 128
#define QQ 40            // R*A
#define KD2 1280         // per-bin GEMM K: 5 rho x 2 part x 128 f
#define SIG_BLOCKS 1500  // 4 points x 2 rho-halves per block
#define W2_BLOCKS 128    // 2 j per block
#define CCQ 0.70710678118654752f
#define RT2 1.41421356237309515f

#define AHS ((size_t)N_PTS * KD2)  // per-bin Ahat elems
#define BHS ((size_t)512 * KD2)    // per-bin Bhat elems

typedef __bf16 bf16_t;
typedef __bf16 bf16x4 __attribute__((ext_vector_type(4)));
typedef __bf16 bf16x8 __attribute__((ext_vector_type(8)));
typedef float f32x2 __attribute__((ext_vector_type(2)));
typedef float f32x4 __attribute__((ext_vector_type(4)));

#define GLOAD_LDS16(g, l)                                              \
  __builtin_amdgcn_global_load_lds(                                    \
      (const __attribute__((address_space(1))) void*)(g),              \
      (__attribute__((address_space(3))) void*)(l), 16, 0, 0)

// 8-point real DFT, X[k] = sum_a x[a] e^{-2pi i k a/8} (verified R8).
#define DFT8V(xx, c, X0, X4, Xr1, Xi1, Xr2, Xi2, Xr3, Xi3)             \
  {                                                                    \
    const float s0_ = xx[0][c] + xx[4][c], s1_ = xx[1][c] + xx[5][c];  \
    const float s2_ = xx[2][c] + xx[6][c], s3_ = xx[3][c] + xx[7][c];  \
    const float d0_ = xx[0][c] - xx[4][c], d1_ = xx[1][c] - xx[5][c];  \
    const float d2_ = xx[2][c] - xx[6][c], d3_ = xx[3][c] - xx[7][c];  \
    const float e_ = CCQ * (d1_ - d3_), o_ = CCQ * (d1_ + d3_);        \
    X0 = (s0_ + s2_) + (s1_ + s3_);                                    \
    X4 = (s0_ + s2_) - (s1_ + s3_);                                    \
    Xr2 = s0_ - s2_; Xi2 = s3_ - s1_;                                  \
    Xr1 = d0_ + e_;  Xi1 = -(o_ + d2_);                                \
    Xr3 = d0_ - e_;  Xi3 = d2_ - o_;                                   \
  }

#define PACK4NT(dst, X)                                                \
  {                                                                    \
    bf16x4 pv_;                                                        \
    pv_[0] = (bf16_t)X[0]; pv_[1] = (bf16_t)X[1];                      \
    pv_[2] = (bf16_t)X[2]; pv_[3] = (bf16_t)X[3];                      \
    __builtin_nontemporal_store(pv_, (bf16x4*)(dst));                  \
  }

// ------------------------------------------- mesh f32 -> bf16 (1.5 MB)
__global__ __launch_bounds__(256) void mesh16_kernel(
    const float* __restrict__ mesh, bf16_t* __restrict__ mesh16) {
  const int i = blockIdx.x * 256 + threadIdx.x;  // 192000 float4 groups
  const float4 v = ((const float4*)mesh)[i];
  bf16x4 o;
  o[0] = (bf16_t)v.x; o[1] = (bf16_t)v.y;
  o[2] = (bf16_t)v.z; o[3] = (bf16_t)v.w;
  ((bf16x4*)mesh16)[i] = o;  // normal store: want it L2-warm for prep
}

// ------------------------------------------------------- FFT prep pass
// blocks [0,1500): 4 points; 256 thr = 8 slots x 32 f4-lanes, slot =
//   (point, rho-half {0,1,2}/{3,4}). Register-direct: bf16x4 mesh gathers
//   (L2-hit), DFT8 in regs, nontemporal bf16x4 stores to 4 bins.
// blocks [1500,1628): Bhat (rot=0 cols) -> DFT -> 4 bins (x 1/8 norm),
//   kw via nontemporal loads, Bhat via nontemporal stores.
__global__ __launch_bounds__(256) void prep_fft_kernel(
    const bf16_t* __restrict__ mesh16, const float* __restrict__ bary,
    const float* __restrict__ kw, const float* __restrict__ interp,
    bf16_t* __restrict__ Ahat, bf16_t* __restrict__ Bhat) {
  __shared__ float sI[RR * AA * QQ];  // w2 branch only
  const int bx = blockIdx.x;
  const int tid = threadIdx.x;

  if (bx < SIG_BLOCKS) {
    const int slot = tid >> 5;   // 0..7
    const int l = tid & 31;      // f = l*4
    const int n = bx * 4 + (slot >> 1);
    const int rh = slot & 1;     // 0 -> rho 0..2, 1 -> rho 3..4
    const float* bn = bary + (size_t)n * (QQ * 6);
    bf16_t* an = Ahat + (size_t)n * KD2 + l * 4;
    const int rho_beg = rh ? 3 : 0;
    const int rho_end = rh ? 5 : 3;
    for (int rho = rho_beg; rho < rho_end; ++rho) {
      float x[8][4];
#pragma unroll
      for (int a = 0; a < 8; ++a) {
        const float* b = bn + (rho * 8 + a) * 6;  // uniform in 32-lane group
        const f32x2 p0 = __builtin_nontemporal_load((const f32x2*)b);
        const f32x2 p1 = __builtin_nontemporal_load((const f32x2*)(b + 2));
        const f32x2 p2 = __builtin_nontemporal_load((const f32x2*)(b + 4));
        const bf16x4 v0 =
            *(const bf16x4*)(mesh16 + (size_t)((int)p0[0]) * FF + l * 4);
        const bf16x4 v1 =
            *(const bf16x4*)(mesh16 + (size_t)((int)p1[0]) * FF + l * 4);
        const bf16x4 v2 =
            *(const bf16x4*)(mesh16 + (size_t)((int)p2[0]) * FF + l * 4);
#pragma unroll
        for (int c = 0; c < 4; ++c)
          x[a][c] = p0[1] * (float)v0[c] + p1[1] * (float)v1[c] +
                    p2[1] * (float)v2[c];
      }
      float X0[4], X4[4], Xr1[4], Xi1[4], Xr2[4], Xi2[4], Xr3[4], Xi3[4];
#pragma unroll
      for (int c = 0; c < 4; ++c)
        DFT8V(x, c, X0[c], X4[c], Xr1[c], Xi1[c], Xr2[c], Xi2[c], Xr3[c],
              Xi3[c]);
      bf16_t* dst = an + rho * 256;
      PACK4NT(dst, X0);                PACK4NT(dst + 128, X4);
      PACK4NT(dst + AHS, Xr1);         PACK4NT(dst + AHS + 128, Xi1);
      PACK4NT(dst + 2 * AHS, Xr2);     PACK4NT(dst + 2 * AHS + 128, Xi2);
      PACK4NT(dst + 3 * AHS, Xr3);     PACK4NT(dst + 3 * AHS + 128, Xi3);
    }
  } else {
    // ---- B side: two j columns per block (128 threads each).
    const int j = (bx - SIG_BLOCKS) * 2 + (tid >> 7);  // 0..255
    const int f = tid & 127;
    for (int i = tid; i < RR * AA * QQ; i += 256) sI[i] = interp[i];
    __syncthreads();
    const int o = (j >> 1) & 127;
    const int k = j & 1;
    float acc[QQ];
#pragma unroll
    for (int q = 0; q < QQ; ++q) acc[q] = 0.f;
    for (int r = 0; r < RR; ++r) {
      for (int a = 0; a < AA; ++a) {
        const float kv = __builtin_nontemporal_load(
            &kw[((size_t)((r * AA + a) * 2 + k) * OO + o) * FF + f]);
        const float4* ip = (const float4*)(sI + (r * AA + a) * QQ);
#pragma unroll
        for (int q4 = 0; q4 < QQ / 4; ++q4) {
          const float4 w4 = ip[q4];
          acc[q4 * 4 + 0] += w4.x * kv;
          acc[q4 * 4 + 1] += w4.y * kv;
          acc[q4 * 4 + 2] += w4.z * kv;
          acc[q4 * 4 + 3] += w4.w * kv;
        }
      }
    }
    // DFT over a; 1/8 normalization folded in (packing verified R8).
    const float SC = 0.125f;
    bf16_t* b1p = Bhat + (size_t)j * KD2 + f;
    bf16_t* b2p = Bhat + (size_t)(256 + j) * KD2 + f;
#define NTS(p, v) __builtin_nontemporal_store((bf16_t)(v), (p))
#pragma unroll
    for (int rho = 0; rho < RR; ++rho) {
      float xx[8][1];
#pragma unroll
      for (int a = 0; a < 8; ++a) xx[a][0] = acc[rho * 8 + a];
      float Y0, Y4, Yr1, Yi1, Yr2, Yi2, Yr3, Yi3;
      DFT8V(xx, 0, Y0, Y4, Yr1, Yi1, Yr2, Yi2, Yr3, Yi3);
      const int off = rho * 256;
      NTS(b1p + off, Y0 * SC);             NTS(b1p + off + 128, 0.f);
      NTS(b2p + off, 0.f);                 NTS(b2p + off + 128, Y4 * SC);
      NTS(b1p + BHS + off, Yr1 * SC);      NTS(b1p + BHS + off + 128, Yi1 * SC);
      NTS(b2p + BHS + off, Yi1 * SC);      NTS(b2p + BHS + off + 128, -Yr1 * SC);
      NTS(b1p + 2 * BHS + off, Yr2 * SC);  NTS(b1p + 2 * BHS + off + 128, Yi2 * SC);
      NTS(b2p + 2 * BHS + off, Yi2 * SC);  NTS(b2p + 2 * BHS + off + 128, -Yr2 * SC);
      NTS(b1p + 3 * BHS + off, Yr3 * SC);  NTS(b1p + 3 * BHS + off + 128, Yi3 * SC);
      NTS(b2p + 3 * BHS + off, Yi3 * SC);  NTS(b2p + 3 * BHS + off + 128, -Yr3 * SC);
    }
#undef NTS
  }
}

// --------------------------------------- fused GEMM + iDFT + epilogue
// Grid 768: xcd=L&7, t=L>>3; slab g=xcd+8*(t>>4) (0..47), j-tile jt=t&15.
// Block = 128m x 16j; B tile = 32 cols (Re Z at col j, Im Z at 256+j ->
// same lane holds Re/Im of the same j). Bins sequential; per-bin iDFT fold
// into 8-rot register accumulator (verified R9). BK=128: 10 kk iters/bin,
// 16 MFMAs per barrier pair. 4-bit XOR chunk swizzle (2 lanes/bank).
__global__ __launch_bounds__(256, 3) void gemm_fused_fft_kernel(
    const bf16_t* __restrict__ Ahat, const bf16_t* __restrict__ Bhat,
    const float* __restrict__ bias, float* __restrict__ out) {
  const int L = blockIdx.x;
  const int xcd = L & 7;
  const int t = L >> 3;                // 0..95
  const int g = xcd + 8 * (t >> 4);    // 0..47
  const int jt = t & 15;
  const int m0 = g * 128;
  if (m0 >= N_PTS) return;
  const int j0 = jt * 16;

  __shared__ bf16_t As[128 * 128];  // 32 KB
  __shared__ bf16_t Bs[32 * 128];   // 8 KB
  const int tid = threadIdx.x;
  const int wave = tid >> 6;
  const int lane = tid & 63;
  const int quad = lane >> 4;
  const int tl = lane & 15;
  const int wm = wave * 32;
  const int srow4 = lane >> 4;  // 0..3 row within 4-row staging group
  const int c16 = lane & 15;    // chunk position 0..15

  static const float CF[4][8] = {
      {1, 1, 1, 1, 1, 1, 1, 1},
      {2, RT2, 0, -RT2, -2, -RT2, 0, RT2},
      {2, 0, -2, 0, 2, 0, -2, 0},
      {2, -RT2, 0, RT2, -2, RT2, 0, -RT2}};
  static const float SF[4][8] = {
      {1, -1, 1, -1, 1, -1, 1, -1},
      {0, -RT2, -2, -RT2, 0, RT2, 2, RT2},
      {0, -2, 0, 2, 0, -2, 0, 2},
      {0, -RT2, 2, -RT2, 0, RT2, -2, RT2}};

  f32x4 oacc[8][2];
#pragma unroll
  for (int rot = 0; rot < 8; ++rot)
#pragma unroll
    for (int mm = 0; mm < 2; ++mm) oacc[rot][mm] = {0.f, 0.f, 0.f, 0.f};

#pragma unroll
  for (int b = 0; b < 4; ++b) {
    const bf16_t* A = Ahat + (size_t)b * AHS;
    const bf16_t* B = Bhat + (size_t)b * BHS;
    f32x4 z[2][2];
#pragma unroll
    for (int mm = 0; mm < 2; ++mm)
#pragma unroll
      for (int cc = 0; cc < 2; ++cc) z[mm][cc] = {0.f, 0.f, 0.f, 0.f};

    for (int kk = 0; kk < KD2; kk += 128) {
      __syncthreads();
      // A: 8 insts/wave, each 4 rows x 16 chunks; swizzle sc = c ^ (row&15)
#pragma unroll
      for (int i = 0; i < 8; ++i) {
        const int row0 = wave * 32 + i * 4;     // wave-uniform LDS base
        const int arow = row0 + srow4;          // per-lane
        int gm = m0 + arow;
        gm = gm < N_PTS ? gm : (N_PTS - 1);
        const int sc = c16 ^ (arow & 15);
        GLOAD_LDS16(A + (size_t)gm * KD2 + kk + sc * 8, As + row0 * 128);
      }
      // B: 2 insts/wave over the 32-row tile
#pragma unroll
      for (int i = 0; i < 2; ++i) {
        const int row0 = wave * 8 + i * 4;
        const int brow = row0 + srow4;          // 0..31
        const int col = brow < 16 ? (j0 + brow) : (256 + j0 + (brow - 16));
        const int sc = c16 ^ (brow & 15);
        GLOAD_LDS16(B + (size_t)col * KD2 + kk + sc * 8, Bs + row0 * 128);
      }
      __syncthreads();
#pragma unroll
      for (int ks = 0; ks < 4; ++ks) {
        const int ch = (((ks * 4 + quad) ^ tl) * 8);
        bf16x8 af[2], bfr[2];
        af[0] = *(const bf16x8*)(As + (wm + tl) * 128 + ch);
        af[1] = *(const bf16x8*)(As + (wm + 16 + tl) * 128 + ch);
        bfr[0] = *(const bf16x8*)(Bs + tl * 128 + ch);
        bfr[1] = *(const bf16x8*)(Bs + (16 + tl) * 128 + ch);
#pragma unroll
        for (int mm = 0; mm < 2; ++mm)
#pragma unroll
          for (int cc = 0; cc < 2; ++cc)
            z[mm][cc] = __builtin_amdgcn_mfma_f32_16x16x32_bf16(
                af[mm], bfr[cc], z[mm][cc], 0, 0, 0);
      }
    }
    // fold this bin into the 8-rot accumulator (iDFT, verified R8/R9)
#pragma unroll
    for (int rot = 0; rot < 8; ++rot) {
      const float cf = CF[b][rot], sf = SF[b][rot];
#pragma unroll
      for (int mm = 0; mm < 2; ++mm)
#pragma unroll
        for (int r = 0; r < 4; ++r)
          oacc[rot][mm][r] += cf * z[mm][0][r] + sf * z[mm][1][r];
    }
  }

  // epilogue: v=relu(oacc+40*bias[k,o]); lanes (tl, tl^1)=(k0,k1) of same o
  const int j = j0 + tl;  // 0..255
  const float bb = 40.0f * bias[((j & 1) << 7) | (j >> 1)];
  const int o = j >> 1;
#pragma unroll
  for (int rot = 0; rot < 8; ++rot)
#pragma unroll
    for (int mm = 0; mm < 2; ++mm)
#pragma unroll
      for (int r = 0; r < 4; ++r) {
        const int mrow = m0 + wm + mm * 16 + quad * 4 + r;
        float v = oacc[rot][mm][r] + bb;
        v = v > 0.f ? v : 0.f;
        const float vs = v + __shfl_xor(v, 1, 64);
        if (((lane & 1) == 0) && (mrow < N_PTS))
          out[(size_t)mrow * 1024 + rot * 128 + o] = vs;
      }
}

extern "C" void kernel_launch(void* const* d_in, const int* in_sizes, int n_in,
                              void* d_out, int out_size, void* d_ws,
                              size_t ws_size, hipStream_t stream) {
  const float* mesh = (const float*)d_in[0];    // (6000,128)
  const float* bary = (const float*)d_in[1];    // (6000,5,8,3,2)
  const float* kw = (const float*)d_in[2];      // (5,8,2,128,128)
  const float* bias = (const float*)d_in[3];    // (2,128)
  const float* interp = (const float*)d_in[4];  // (5,8,40)
  float* out = (float*)d_out;                   // (6000,8,128)

  bf16_t* Ahat = (bf16_t*)d_ws;                            // 61.44 MB
  bf16_t* Bhat = (bf16_t*)((char*)d_ws + 4 * AHS * 2);     // +5.24 MB
  bf16_t* mesh16 =
      (bf16_t*)((char*)d_ws + 4 * AHS * 2 + 4 * BHS * 2);  // +1.54 MB

  mesh16_kernel<<<750, 256, 0, stream>>>(mesh, mesh16);
  prep_fft_kernel<<<SIG_BLOCKS + W2_BLOCKS, 256, 0, stream>>>(
      mesh16, bary, kw, interp, Ahat, Bhat);
  gemm_fused_fft_kernel<<<768, 256, 0, stream>>>(Ahat, Bhat, bias, out);
}

// Round 11
// 176.985 us; speedup vs baseline: 1.2031x; 1.2031x over previous
//
#include <hip/hip_runtime.h>
#include <hip/hip_bf16.h>

// ConvIntrinsic: gather+barycentric -> patch-operator -> 8 rotated folds.
// Circular-correlation FFT formulation (verified R8/R9): 8-pt real DFT over
// the angular index on both sides; ĉ[k]=X*[k]Y[k] per bin k={0&4,1,2,3};
// in-register inverse DFT + bias + relu + k-pair fold in the GEMM epilogue.
//
// R11: R10's NT stores reverted (they evicted the producer->consumer Ahat
// from LLC: GEMM FETCH 50->65 MB, 67->100 us). GEMM back to BK=64 but with
// 64-row m-tiles -> grid 1536 (~6 blocks/CU vs 3; the proven parallelism
// lever, no partials). Prep: w2 split 5x finer (640 blocks = j-pair x rho)
// and dispatched FIRST (its 2-wave blocks were a serial tail); mesh cast
// to bf16 once (half gather bytes; numerics proven R10).

#define N_PTS 6000
#define RR 5
#define AA 8
#define FF 128
#define OO 128
#define QQ 40            // R*A
#define KD2 1280         // per-bin GEMM K: 5 rho x 2 part x 128 f
#define W2_BLOCKS 640    // (j-pair 0..127) x (rho 0..4)
#define SIG_BLOCKS 750   // 8 points per block
#define CCQ 0.70710678118654752f
#define RT2 1.41421356237309515f

#define AHS ((size_t)N_PTS * KD2)  // per-bin Ahat elems
#define BHS ((size_t)512 * KD2)    // per-bin Bhat elems

typedef __bf16 bf16_t;
typedef __bf16 bf16x4 __attribute__((ext_vector_type(4)));
typedef __bf16 bf16x8 __attribute__((ext_vector_type(8)));
typedef float f32x4 __attribute__((ext_vector_type(4)));

#define GLOAD_LDS16(g, l)                                              \
  __builtin_amdgcn_global_load_lds(                                    \
      (const __attribute__((address_space(1))) void*)(g),              \
      (__attribute__((address_space(3))) void*)(l), 16, 0, 0)

// 8-point real DFT, X[k] = sum_a x[a] e^{-2pi i k a/8} (verified R8).
#define DFT8V(xx, c, X0, X4, Xr1, Xi1, Xr2, Xi2, Xr3, Xi3)             \
  {                                                                    \
    const float s0_ = xx[0][c] + xx[4][c], s1_ = xx[1][c] + xx[5][c];  \
    const float s2_ = xx[2][c] + xx[6][c], s3_ = xx[3][c] + xx[7][c];  \
    const float d0_ = xx[0][c] - xx[4][c], d1_ = xx[1][c] - xx[5][c];  \
    const float d2_ = xx[2][c] - xx[6][c], d3_ = xx[3][c] - xx[7][c];  \
    const float e_ = CCQ * (d1_ - d3_), o_ = CCQ * (d1_ + d3_);        \
    X0 = (s0_ + s2_) + (s1_ + s3_);                                    \
    X4 = (s0_ + s2_) - (s1_ + s3_);                                    \
    Xr2 = s0_ - s2_; Xi2 = s3_ - s1_;                                  \
    Xr1 = d0_ + e_;  Xi1 = -(o_ + d2_);                                \
    Xr3 = d0_ - e_;  Xi3 = d2_ - o_;                                   \
  }

#define PACK4(dst, X)                                                  \
  {                                                                    \
    bf16x4 pv_;                                                        \
    pv_[0] = (bf16_t)X[0]; pv_[1] = (bf16_t)X[1];                      \
    pv_[2] = (bf16_t)X[2]; pv_[3] = (bf16_t)X[3];                      \
    *(bf16x4*)(dst) = pv_;                                             \
  }

// ------------------------------------------- mesh f32 -> bf16 (1.5 MB)
__global__ __launch_bounds__(256) void mesh16_kernel(
    const float* __restrict__ mesh, bf16_t* __restrict__ mesh16) {
  const int i = blockIdx.x * 256 + threadIdx.x;  // 192000 float4 groups
  const float4 v = ((const float4*)mesh)[i];
  bf16x4 o;
  o[0] = (bf16_t)v.x; o[1] = (bf16_t)v.y;
  o[2] = (bf16_t)v.z; o[3] = (bf16_t)v.w;
  ((bf16x4*)mesh16)[i] = o;  // normal store: L2/LLC-warm for prep
}

// ------------------------------------------------------- FFT prep pass
// blocks [0,640) — FIRST, so their long 2-wave bodies hide under sig:
//   w2 for (j-pair, rho): 8 q-accumulators, DFT8, pack 16 bf16 into Bhat.
// blocks [640,1390): sig for 8 points each; 256 thr = 8 point-slots x 32
//   f4-lanes; register-direct bf16 gathers -> DFT8 -> bf16x4 stores.
__global__ __launch_bounds__(256) void prep_fft_kernel(
    const bf16_t* __restrict__ mesh16, const float* __restrict__ bary,
    const float* __restrict__ kw, const float* __restrict__ interp,
    bf16_t* __restrict__ Ahat, bf16_t* __restrict__ Bhat) {
  __shared__ float sI[QQ * AA];  // 320 floats: interp[.,.,rho*8+a']
  const int bx = blockIdx.x;
  const int tid = threadIdx.x;

  if (bx < W2_BLOCKS) {
    const int rho = bx >> 7;      // 0..4
    const int jp = bx & 127;
    const int j = jp * 2 + (tid >> 7);  // 0..255
    const int f = tid & 127;
    for (int i = tid; i < QQ * AA; i += 256)
      sI[i] = interp[(i >> 3) * QQ + rho * 8 + (i & 7)];
    __syncthreads();
    const int o = (j >> 1) & 127;
    const int k = j & 1;
    float acc[8];
#pragma unroll
    for (int a = 0; a < 8; ++a) acc[a] = 0.f;
    for (int ra = 0; ra < QQ; ++ra) {
      const float kv = kw[((size_t)(ra * 2 + k) * OO + o) * FF + f];
      const float4 c0 = *(const float4*)(sI + ra * 8);
      const float4 c1 = *(const float4*)(sI + ra * 8 + 4);
      acc[0] += c0.x * kv; acc[1] += c0.y * kv;
      acc[2] += c0.z * kv; acc[3] += c0.w * kv;
      acc[4] += c1.x * kv; acc[5] += c1.y * kv;
      acc[6] += c1.z * kv; acc[7] += c1.w * kv;
    }
    float xx[8][1];
#pragma unroll
    for (int a = 0; a < 8; ++a) xx[a][0] = acc[a];
    float Y0, Y4, Yr1, Yi1, Yr2, Yi2, Yr3, Yi3;
    DFT8V(xx, 0, Y0, Y4, Yr1, Yi1, Yr2, Yi2, Yr3, Yi3);
    const float SC = 0.125f;  // 1/8 iDFT normalization
    bf16_t* b1p = Bhat + (size_t)j * KD2 + f;          // col j (Re-type)
    bf16_t* b2p = Bhat + (size_t)(256 + j) * KD2 + f;  // col 256+j (Im-type)
    const int off = rho * 256;
    b1p[off] = (bf16_t)(Y0 * SC);        b1p[off + 128] = (bf16_t)0.f;
    b2p[off] = (bf16_t)0.f;              b2p[off + 128] = (bf16_t)(Y4 * SC);
    b1p[BHS + off] = (bf16_t)(Yr1 * SC);
    b1p[BHS + off + 128] = (bf16_t)(Yi1 * SC);
    b2p[BHS + off] = (bf16_t)(Yi1 * SC);
    b2p[BHS + off + 128] = (bf16_t)(-Yr1 * SC);
    b1p[2 * BHS + off] = (bf16_t)(Yr2 * SC);
    b1p[2 * BHS + off + 128] = (bf16_t)(Yi2 * SC);
    b2p[2 * BHS + off] = (bf16_t)(Yi2 * SC);
    b2p[2 * BHS + off + 128] = (bf16_t)(-Yr2 * SC);
    b1p[3 * BHS + off] = (bf16_t)(Yr3 * SC);
    b1p[3 * BHS + off + 128] = (bf16_t)(Yi3 * SC);
    b2p[3 * BHS + off] = (bf16_t)(Yi3 * SC);
    b2p[3 * BHS + off + 128] = (bf16_t)(-Yr3 * SC);
  } else {
    const int slot = tid >> 5;  // 0..7
    const int l = tid & 31;     // f = l*4
    const int n = (bx - W2_BLOCKS) * 8 + slot;
    const float* bn = bary + (size_t)n * (QQ * 6);
    bf16_t* an = Ahat + (size_t)n * KD2 + l * 4;
#pragma unroll
    for (int rho = 0; rho < RR; ++rho) {
      float x[8][4];
#pragma unroll
      for (int a = 0; a < 8; ++a) {
        const float* b = bn + (rho * 8 + a) * 6;  // uniform in 32-lane group
        const float2 p0 = *(const float2*)(b);
        const float2 p1 = *(const float2*)(b + 2);
        const float2 p2 = *(const float2*)(b + 4);
        const bf16x4 v0 =
            *(const bf16x4*)(mesh16 + (size_t)((int)p0.x) * FF + l * 4);
        const bf16x4 v1 =
            *(const bf16x4*)(mesh16 + (size_t)((int)p1.x) * FF + l * 4);
        const bf16x4 v2 =
            *(const bf16x4*)(mesh16 + (size_t)((int)p2.x) * FF + l * 4);
#pragma unroll
        for (int c = 0; c < 4; ++c)
          x[a][c] = p0.y * (float)v0[c] + p1.y * (float)v1[c] +
                    p2.y * (float)v2[c];
      }
      float X0[4], X4[4], Xr1[4], Xi1[4], Xr2[4], Xi2[4], Xr3[4], Xi3[4];
#pragma unroll
      for (int c = 0; c < 4; ++c)
        DFT8V(x, c, X0[c], X4[c], Xr1[c], Xi1[c], Xr2[c], Xi2[c], Xr3[c],
              Xi3[c]);
      bf16_t* dst = an + rho * 256;
      PACK4(dst, X0);                  PACK4(dst + 128, X4);
      PACK4(dst + AHS, Xr1);           PACK4(dst + AHS + 128, Xi1);
      PACK4(dst + 2 * AHS, Xr2);       PACK4(dst + 2 * AHS + 128, Xi2);
      PACK4(dst + 3 * AHS, Xr3);       PACK4(dst + 3 * AHS + 128, Xi3);
    }
  }
}

// --------------------------------------- fused GEMM + iDFT + epilogue
// Grid 1536: xcd=L&7, t=L>>3 (0..191); slab g=xcd+8*(t>>4) (0..95, 64 rows
// each; g>=94 exits), j-tile jt=t&15. Block = 64m x 16j, 4 waves x 16 rows.
// B tile = 32 cols (Re Z at col j, Im Z at 256+j -> same lane holds Re/Im
// of the same j). Bins sequential; per-bin iDFT fold into the 8-rot
// register accumulator (verified R9). BK=64, XOR chunk swizzle, 12 KB LDS,
// 6 blocks/CU target (the R3/R7 parallelism lever, no partials).
__global__ __launch_bounds__(256, 6) void gemm_fused_fft_kernel(
    const bf16_t* __restrict__ Ahat, const bf16_t* __restrict__ Bhat,
    const float* __restrict__ bias, float* __restrict__ out) {
  const int L = blockIdx.x;
  const int xcd = L & 7;
  const int t = L >> 3;                // 0..191
  const int g = xcd + 8 * (t >> 4);    // 0..95 (64-row slab)
  const int jt = t & 15;
  const int m0 = g * 64;
  if (m0 >= N_PTS) return;
  const int j0 = jt * 16;

  __shared__ bf16_t As[64 * 64];   // 8 KB
  __shared__ bf16_t Bs[32 * 64];   // 4 KB
  const int tid = threadIdx.x;
  const int wave = tid >> 6;
  const int lane = tid & 63;
  const int quad = lane >> 4;
  const int tl = lane & 15;
  const int wm = wave * 16;
  const int srow = lane >> 3;
  const int sc = (lane & 7) ^ srow;

  // this wave's B staging chunk (8 rows of the 32-row B tile)
  const int crow = wave * 8;
  const int colbase = (crow < 16) ? (j0 + crow) : (256 + j0 + (crow - 16));
  const int gcol = colbase + srow;

  static const float CF[4][8] = {
      {1, 1, 1, 1, 1, 1, 1, 1},
      {2, RT2, 0, -RT2, -2, -RT2, 0, RT2},
      {2, 0, -2, 0, 2, 0, -2, 0},
      {2, -RT2, 0, RT2, -2, RT2, 0, -RT2}};
  static const float SF[4][8] = {
      {1, -1, 1, -1, 1, -1, 1, -1},
      {0, -RT2, -2, -RT2, 0, RT2, 2, RT2},
      {0, -2, 0, 2, 0, -2, 0, 2},
      {0, -RT2, 2, -RT2, 0, RT2, -2, RT2}};

  f32x4 oacc[8];
#pragma unroll
  for (int rot = 0; rot < 8; ++rot) oacc[rot] = {0.f, 0.f, 0.f, 0.f};

#pragma unroll
  for (int b = 0; b < 4; ++b) {
    const bf16_t* A = Ahat + (size_t)b * AHS;
    const bf16_t* B = Bhat + (size_t)b * BHS;
    f32x4 z[2];
    z[0] = {0.f, 0.f, 0.f, 0.f};
    z[1] = {0.f, 0.f, 0.f, 0.f};

    for (int kk = 0; kk < KD2; kk += 64) {
      __syncthreads();
#pragma unroll
      for (int i = 0; i < 2; ++i) {
        const int row0 = wave * 16 + i * 8;  // wave-uniform LDS base
        int gm = m0 + row0 + srow;
        gm = gm < N_PTS ? gm : (N_PTS - 1);
        GLOAD_LDS16(A + (size_t)gm * KD2 + kk + sc * 8, As + row0 * 64);
      }
      GLOAD_LDS16(B + (size_t)gcol * KD2 + kk + sc * 8, Bs + crow * 64);
      __syncthreads();
#pragma unroll
      for (int ks = 0; ks < 2; ++ks) {
        const int ch = (((ks * 4 + quad) ^ (tl & 7)) * 8);
        const bf16x8 af = *(const bf16x8*)(As + (wm + tl) * 64 + ch);
        const bf16x8 b0 = *(const bf16x8*)(Bs + tl * 64 + ch);
        const bf16x8 b1 = *(const bf16x8*)(Bs + (16 + tl) * 64 + ch);
        z[0] = __builtin_amdgcn_mfma_f32_16x16x32_bf16(af, b0, z[0], 0, 0, 0);
        z[1] = __builtin_amdgcn_mfma_f32_16x16x32_bf16(af, b1, z[1], 0, 0, 0);
      }
    }
    // fold this bin into the 8-rot accumulator (iDFT, verified R8/R9)
#pragma unroll
    for (int rot = 0; rot < 8; ++rot) {
      const float cf = CF[b][rot], sf = SF[b][rot];
#pragma unroll
      for (int r = 0; r < 4; ++r)
        oacc[rot][r] += cf * z[0][r] + sf * z[1][r];
    }
  }

  // epilogue: v=relu(oacc+40*bias[k,o]); lanes (tl, tl^1)=(k0,k1) of same o
  const int j = j0 + tl;  // 0..255
  const float bb = 40.0f * bias[((j & 1) << 7) | (j >> 1)];
  const int o = j >> 1;
#pragma unroll
  for (int rot = 0; rot < 8; ++rot)
#pragma unroll
    for (int r = 0; r < 4; ++r) {
      const int mrow = m0 + wm + quad * 4 + r;
      float v = oacc[rot][r] + bb;
      v = v > 0.f ? v : 0.f;
      const float vs = v + __shfl_xor(v, 1, 64);
      if (((lane & 1) == 0) && (mrow < N_PTS))
        out[(size_t)mrow * 1024 + rot * 128 + o] = vs;
    }
}

extern "C" void kernel_launch(void* const* d_in, const int* in_sizes, int n_in,
                              void* d_out, int out_size, void* d_ws,
                              size_t ws_size, hipStream_t stream) {
  const float* mesh = (const float*)d_in[0];    // (6000,128)
  const float* bary = (const float*)d_in[1];    // (6000,5,8,3,2)
  const float* kw = (const float*)d_in[2];      // (5,8,2,128,128)
  const float* bias = (const float*)d_in[3];    // (2,128)
  const float* interp = (const float*)d_in[4];  // (5,8,40)
  float* out = (float*)d_out;                   // (6000,8,128)

  bf16_t* Ahat = (bf16_t*)d_ws;                            // 61.44 MB
  bf16_t* Bhat = (bf16_t*)((char*)d_ws + 4 * AHS * 2);     // +5.24 MB
  bf16_t* mesh16 =
      (bf16_t*)((char*)d_ws + 4 * AHS * 2 + 4 * BHS * 2);  // +1.54 MB

  mesh16_kernel<<<750, 256, 0, stream>>>(mesh, mesh16);
  prep_fft_kernel<<<W2_BLOCKS + SIG_BLOCKS, 256, 0, stream>>>(
      mesh16, bary, kw, interp, Ahat, Bhat);
  gemm_fused_fft_kernel<<<1536, 256, 0, stream>>>(Ahat, Bhat, bias, out);
}

// Round 12
// 167.347 us; speedup vs baseline: 1.2724x; 1.0576x over previous
//
#include <hip/hip_runtime.h>
#include <hip/hip_bf16.h>

// ConvIntrinsic: gather+barycentric -> patch-operator -> 8 rotated folds.
// Circular-correlation FFT formulation (verified R8/R9): 8-pt real DFT over
// the angular index on both sides; ĉ[k]=X*[k]Y[k] per bin k={0&4,1,2,3};
// iDFT + bias + relu + k-pair fold give the 8 rotation outputs.
//
// R12: bins split ACROSS blocks (grid 768 x 4 bins) instead of sequential
// within one block. R11 showed the fused kernel is LDS-read-pipe-bound and
// register-capped (8-rot accumulators cost 32 VGPR per m-frag, blocking
// tile growth). Per-bin blocks need only z[2][2]=16 acc VGPRs -> ~8
// blocks/CU, 20 kk iters; raw Z (f32, 49 MB) dumped coalesced; a separate
// 3000-block fold kernel does iDFT+bias+relu+k-fold (74 MB streamed).
// Prep = R9's exact version (f32 mesh gathers; absmax 0.0625 proven).

#define N_PTS 6000
#define MR 6016          // padded rows per Z plane
#define RR 5
#define AA 8
#define FF 128
#define OO 128
#define QQ 40            // R*A
#define KD2 1280         // per-bin GEMM K: 5 rho x 2 part x 128 f
#define SIG_BLOCKS 750   // 8 points per block
#define W2_BLOCKS 128    // 2 j per block
#define CCQ 0.70710678118654752f
#define RT2 1.41421356237309515f

#define AHS ((size_t)N_PTS * KD2)  // per-bin Ahat elems
#define BHS ((size_t)512 * KD2)    // per-bin Bhat elems

typedef __bf16 bf16_t;
typedef __bf16 bf16x4 __attribute__((ext_vector_type(4)));
typedef __bf16 bf16x8 __attribute__((ext_vector_type(8)));
typedef float f32x4 __attribute__((ext_vector_type(4)));

#define GLOAD_LDS16(g, l)                                              \
  __builtin_amdgcn_global_load_lds(                                    \
      (const __attribute__((address_space(1))) void*)(g),              \
      (__attribute__((address_space(3))) void*)(l), 16, 0, 0)

// 8-point real DFT, X[k] = sum_a x[a] e^{-2pi i k a/8} (verified R8).
#define DFT8V(xx, c, X0, X4, Xr1, Xi1, Xr2, Xi2, Xr3, Xi3)             \
  {                                                                    \
    const float s0_ = xx[0][c] + xx[4][c], s1_ = xx[1][c] + xx[5][c];  \
    const float s2_ = xx[2][c] + xx[6][c], s3_ = xx[3][c] + xx[7][c];  \
    const float d0_ = xx[0][c] - xx[4][c], d1_ = xx[1][c] - xx[5][c];  \
    const float d2_ = xx[2][c] - xx[6][c], d3_ = xx[3][c] - xx[7][c];  \
    const float e_ = CCQ * (d1_ - d3_), o_ = CCQ * (d1_ + d3_);        \
    X0 = (s0_ + s2_) + (s1_ + s3_);                                    \
    X4 = (s0_ + s2_) - (s1_ + s3_);                                    \
    Xr2 = s0_ - s2_; Xi2 = s3_ - s1_;                                  \
    Xr1 = d0_ + e_;  Xi1 = -(o_ + d2_);                                \
    Xr3 = d0_ - e_;  Xi3 = d2_ - o_;                                   \
  }

#define PACK4(dst, X)                                                  \
  {                                                                    \
    bf16x4 pv_;                                                        \
    pv_[0] = (bf16_t)X[0]; pv_[1] = (bf16_t)X[1];                      \
    pv_[2] = (bf16_t)X[2]; pv_[3] = (bf16_t)X[3];                      \
    *(bf16x4*)(dst) = pv_;                                             \
  }

// ------------------------------------------------------- FFT prep pass
// (R9 verbatim.) blocks [0,750): 8 points each; 256 thr = 8 point-slots x
// 32 f4-lanes; register-direct f32 gathers -> DFT8 -> bf16x4 stores.
// blocks [750,878): Bhat (rot=0 cols) -> DFT -> 4 bins (x 1/8 norm).
__global__ __launch_bounds__(256) void prep_fft_kernel(
    const float* __restrict__ mesh, const float* __restrict__ bary,
    const float* __restrict__ kw, const float* __restrict__ interp,
    bf16_t* __restrict__ Ahat, bf16_t* __restrict__ Bhat) {
  __shared__ float sI[RR * AA * QQ];  // w2 branch only
  const int bx = blockIdx.x;
  const int tid = threadIdx.x;

  if (bx < SIG_BLOCKS) {
    const int slot = tid >> 5;  // 0..7
    const int l = tid & 31;     // f = l*4
    const int n = bx * 8 + slot;
    const float* bn = bary + (size_t)n * (QQ * 6);
    bf16_t* an = Ahat + (size_t)n * KD2 + l * 4;
#pragma unroll
    for (int rho = 0; rho < RR; ++rho) {
      float x[8][4];
#pragma unroll
      for (int a = 0; a < 8; ++a) {
        const float* b = bn + (rho * 8 + a) * 6;  // uniform in 32-lane group
        const float2 p0 = *(const float2*)(b);
        const float2 p1 = *(const float2*)(b + 2);
        const float2 p2 = *(const float2*)(b + 4);
        const float4 v0 =
            *(const float4*)(mesh + (size_t)((int)p0.x) * FF + l * 4);
        const float4 v1 =
            *(const float4*)(mesh + (size_t)((int)p1.x) * FF + l * 4);
        const float4 v2 =
            *(const float4*)(mesh + (size_t)((int)p2.x) * FF + l * 4);
        x[a][0] = p0.y * v0.x + p1.y * v1.x + p2.y * v2.x;
        x[a][1] = p0.y * v0.y + p1.y * v1.y + p2.y * v2.y;
        x[a][2] = p0.y * v0.z + p1.y * v1.z + p2.y * v2.z;
        x[a][3] = p0.y * v0.w + p1.y * v1.w + p2.y * v2.w;
      }
      float X0[4], X4[4], Xr1[4], Xi1[4], Xr2[4], Xi2[4], Xr3[4], Xi3[4];
#pragma unroll
      for (int c = 0; c < 4; ++c)
        DFT8V(x, c, X0[c], X4[c], Xr1[c], Xi1[c], Xr2[c], Xi2[c], Xr3[c],
              Xi3[c]);
      bf16_t* dst = an + rho * 256;
      PACK4(dst, X0);                  PACK4(dst + 128, X4);
      PACK4(dst + AHS, Xr1);           PACK4(dst + AHS + 128, Xi1);
      PACK4(dst + 2 * AHS, Xr2);       PACK4(dst + 2 * AHS + 128, Xi2);
      PACK4(dst + 3 * AHS, Xr3);       PACK4(dst + 3 * AHS + 128, Xi3);
    }
  } else {
    // ---- B side: two j columns per block (128 threads each).
    const int j = (bx - SIG_BLOCKS) * 2 + (tid >> 7);  // 0..255
    const int f = tid & 127;
    for (int i = tid; i < RR * AA * QQ; i += 256) sI[i] = interp[i];
    __syncthreads();
    const int o = (j >> 1) & 127;
    const int k = j & 1;
    float acc[QQ];
#pragma unroll
    for (int q = 0; q < QQ; ++q) acc[q] = 0.f;
    for (int r = 0; r < RR; ++r) {
      for (int a = 0; a < AA; ++a) {
        const float kv =
            kw[((size_t)((r * AA + a) * 2 + k) * OO + o) * FF + f];
        const float4* ip = (const float4*)(sI + (r * AA + a) * QQ);
#pragma unroll
        for (int q4 = 0; q4 < QQ / 4; ++q4) {
          const float4 w4 = ip[q4];
          acc[q4 * 4 + 0] += w4.x * kv;
          acc[q4 * 4 + 1] += w4.y * kv;
          acc[q4 * 4 + 2] += w4.z * kv;
          acc[q4 * 4 + 3] += w4.w * kv;
        }
      }
    }
    // DFT over a; 1/8 normalization folded in (packing verified R8).
    const float SC = 0.125f;
    bf16_t* b1p = Bhat + (size_t)j * KD2 + f;          // col j (Re-type)
    bf16_t* b2p = Bhat + (size_t)(256 + j) * KD2 + f;  // col 256+j (Im-type)
#pragma unroll
    for (int rho = 0; rho < RR; ++rho) {
      float xx[8][1];
#pragma unroll
      for (int a = 0; a < 8; ++a) xx[a][0] = acc[rho * 8 + a];
      float Y0, Y4, Yr1, Yi1, Yr2, Yi2, Yr3, Yi3;
      DFT8V(xx, 0, Y0, Y4, Yr1, Yi1, Yr2, Yi2, Yr3, Yi3);
      const int off = rho * 256;
      b1p[off] = (bf16_t)(Y0 * SC);        b1p[off + 128] = (bf16_t)0.f;
      b2p[off] = (bf16_t)0.f;              b2p[off + 128] = (bf16_t)(Y4 * SC);
      b1p[BHS + off] = (bf16_t)(Yr1 * SC);
      b1p[BHS + off + 128] = (bf16_t)(Yi1 * SC);
      b2p[BHS + off] = (bf16_t)(Yi1 * SC);
      b2p[BHS + off + 128] = (bf16_t)(-Yr1 * SC);
      b1p[2 * BHS + off] = (bf16_t)(Yr2 * SC);
      b1p[2 * BHS + off + 128] = (bf16_t)(Yi2 * SC);
      b2p[2 * BHS + off] = (bf16_t)(Yi2 * SC);
      b2p[2 * BHS + off + 128] = (bf16_t)(-Yr2 * SC);
      b1p[3 * BHS + off] = (bf16_t)(Yr3 * SC);
      b1p[3 * BHS + off + 128] = (bf16_t)(Yi3 * SC);
      b2p[3 * BHS + off] = (bf16_t)(Yi3 * SC);
      b2p[3 * BHS + off + 128] = (bf16_t)(-Yr3 * SC);
    }
  }
}

// ----------------------------------------- per-bin GEMM (Z partials)
// Grid (768, 4 bins). x-mapping = R9's proven XCD swizzle: xcd=L&7,
// t=L>>3, slab g=xcd+8*(t>>4) (16 j-tiles share one A-slab per XCD),
// jt=t&15. Block = 128m x 16j, one bin, K=1280 (20 BK=64 iters).
// z[2][2] accs only -> ~60 VGPR, 20 KB LDS -> ~8 blocks/CU.
// Z layout: plane p = bin*2+cc (cc0=Re-type col j, cc1=Im-type col 256+j),
// Z[p][m(MR)][j(256)] f32, coalesced 64 B stores; rows >= N_PTS scratch.
__global__ __launch_bounds__(256, 6) void gemm_bin_kernel(
    const bf16_t* __restrict__ Ahat, const bf16_t* __restrict__ Bhat,
    float* __restrict__ Z) {
  const int L = blockIdx.x;
  const int bin = blockIdx.y;
  const int xcd = L & 7;
  const int t = L >> 3;                // 0..95
  const int g = xcd + 8 * (t >> 4);    // 0..47
  const int jt = t & 15;
  const int m0 = g * 128;
  if (m0 >= N_PTS) return;
  const int j0 = jt * 16;
  const bf16_t* A = Ahat + (size_t)bin * AHS;
  const bf16_t* B = Bhat + (size_t)bin * BHS;

  __shared__ bf16_t As[128 * 64];  // 16 KB
  __shared__ bf16_t Bs[32 * 64];   // 4 KB
  const int tid = threadIdx.x;
  const int wave = tid >> 6;
  const int lane = tid & 63;
  const int quad = lane >> 4;
  const int tl = lane & 15;
  const int wm = wave * 32;
  const int srow = lane >> 3;
  const int sc = (lane & 7) ^ srow;

  // this wave's B staging chunk (8 rows of the 32-row B tile)
  const int crow = wave * 8;
  const int colbase = (crow < 16) ? (j0 + crow) : (256 + j0 + (crow - 16));
  const int gcol = colbase + srow;

  f32x4 z[2][2];
#pragma unroll
  for (int mm = 0; mm < 2; ++mm)
#pragma unroll
    for (int cc = 0; cc < 2; ++cc) z[mm][cc] = {0.f, 0.f, 0.f, 0.f};

  for (int kk = 0; kk < KD2; kk += 64) {
    __syncthreads();
#pragma unroll
    for (int i = 0; i < 4; ++i) {
      const int row = wave * 32 + i * 8;  // wave-uniform LDS base
      int gm = m0 + row + srow;
      gm = gm < N_PTS ? gm : (N_PTS - 1);
      GLOAD_LDS16(A + (size_t)gm * KD2 + kk + sc * 8, As + row * 64);
    }
    GLOAD_LDS16(B + (size_t)gcol * KD2 + kk + sc * 8, Bs + crow * 64);
    __syncthreads();
#pragma unroll
    for (int ks = 0; ks < 2; ++ks) {
      const int ch = (((ks * 4 + quad) ^ (tl & 7)) * 8);
      bf16x8 af[2], bfr[2];
      af[0] = *(const bf16x8*)(As + (wm + tl) * 64 + ch);
      af[1] = *(const bf16x8*)(As + (wm + 16 + tl) * 64 + ch);
      bfr[0] = *(const bf16x8*)(Bs + tl * 64 + ch);
      bfr[1] = *(const bf16x8*)(Bs + (16 + tl) * 64 + ch);
#pragma unroll
      for (int mm = 0; mm < 2; ++mm)
#pragma unroll
        for (int cc = 0; cc < 2; ++cc)
          z[mm][cc] = __builtin_amdgcn_mfma_f32_16x16x32_bf16(
              af[mm], bfr[cc], z[mm][cc], 0, 0, 0);
    }
  }

  // dump Z: C-layout col=lane&15 -> j=j0+tl; row=wm+mm*16+quad*4+r.
#pragma unroll
  for (int cc = 0; cc < 2; ++cc) {
    float* zp = Z + ((size_t)(bin * 2 + cc) * MR) * 256 + j0 + tl;
#pragma unroll
    for (int mm = 0; mm < 2; ++mm)
#pragma unroll
      for (int r = 0; r < 4; ++r) {
        const int mrow = m0 + wm + mm * 16 + quad * 4 + r;
        zp[(size_t)mrow * 256] = z[mm][cc][r];  // rows >= N_PTS = scratch
      }
  }
}

// ----------------------- fold: iDFT + bias + relu + k-pair fold
// Thread -> (m, o). Reads 8 float2 (Re/Im x 4 bins, j={2o,2o+1}),
// computes 8 rots x 2 k, relu, pair-sum, writes 8 f32. All coalesced.
// c_rot = sum_b CF[b][rot]*Re_b + SF[b][rot]*Im_b (verified R8/R9).
__global__ __launch_bounds__(256) void fold_kernel(
    const float* __restrict__ Z, const float* __restrict__ bias,
    float* __restrict__ out) {
  const int T = blockIdx.x * 256 + threadIdx.x;  // < 768000
  const int m = T >> 7;
  const int o = T & 127;

  static const float CF[4][8] = {
      {1, 1, 1, 1, 1, 1, 1, 1},
      {2, RT2, 0, -RT2, -2, -RT2, 0, RT2},
      {2, 0, -2, 0, 2, 0, -2, 0},
      {2, -RT2, 0, RT2, -2, RT2, 0, -RT2}};
  static const float SF[4][8] = {
      {1, -1, 1, -1, 1, -1, 1, -1},
      {0, -RT2, -2, -RT2, 0, RT2, 2, RT2},
      {0, -2, 0, 2, 0, -2, 0, 2},
      {0, -RT2, 2, -RT2, 0, RT2, -2, RT2}};

  float re[4][2], im[4][2];
#pragma unroll
  for (int b = 0; b < 4; ++b) {
    const float2 vr = *(const float2*)(
        Z + ((size_t)(b * 2) * MR + m) * 256 + 2 * o);
    const float2 vi = *(const float2*)(
        Z + ((size_t)(b * 2 + 1) * MR + m) * 256 + 2 * o);
    re[b][0] = vr.x; re[b][1] = vr.y;
    im[b][0] = vi.x; im[b][1] = vi.y;
  }
  const float b0 = 40.0f * bias[o];
  const float b1 = 40.0f * bias[128 + o];
  float* op = out + (size_t)m * 1024 + o;
#pragma unroll
  for (int rot = 0; rot < 8; ++rot) {
    float c0 = 0.f, c1 = 0.f;
#pragma unroll
    for (int b = 0; b < 4; ++b) {
      c0 += CF[b][rot] * re[b][0] + SF[b][rot] * im[b][0];
      c1 += CF[b][rot] * re[b][1] + SF[b][rot] * im[b][1];
    }
    float v0 = c0 + b0;
    float v1 = c1 + b1;
    v0 = v0 > 0.f ? v0 : 0.f;
    v1 = v1 > 0.f ? v1 : 0.f;
    op[rot * 128] = v0 + v1;
  }
}

extern "C" void kernel_launch(void* const* d_in, const int* in_sizes, int n_in,
                              void* d_out, int out_size, void* d_ws,
                              size_t ws_size, hipStream_t stream) {
  const float* mesh = (const float*)d_in[0];    // (6000,128)
  const float* bary = (const float*)d_in[1];    // (6000,5,8,3,2)
  const float* kw = (const float*)d_in[2];      // (5,8,2,128,128)
  const float* bias = (const float*)d_in[3];    // (2,128)
  const float* interp = (const float*)d_in[4];  // (5,8,40)
  float* out = (float*)d_out;                   // (6000,8,128)

  bf16_t* Ahat = (bf16_t*)d_ws;                          // 61.44 MB
  bf16_t* Bhat = (bf16_t*)((char*)d_ws + 4 * AHS * 2);   // +5.24 MB
  float* Z =
      (float*)((char*)d_ws + 4 * AHS * 2 + 4 * BHS * 2);  // +49.28 MB

  prep_fft_kernel<<<SIG_BLOCKS + W2_BLOCKS, 256, 0, stream>>>(
      mesh, bary, kw, interp, Ahat, Bhat);
  gemm_bin_kernel<<<dim3(768, 4), 256, 0, stream>>>(Ahat, Bhat, Z);
  fold_kernel<<<3000, 256, 0, stream>>>(Z, bias, out);
}